// Round 1
// baseline (422.417 us; speedup 1.0000x reference)
//
#include <hip/hip_runtime.h>
#include <math.h>

// ArmInt: per-row integerized MLP, B rows x 32 features.
//   h = x*256
//   h = relu(round_half_away((h@W0^T + b0 + 256*h)/256))
//   h = relu(round_half_away((h@W1^T + b1 + 256*h)/256))
//   o = round_half_away((h@Wout^T + bout)/256) / 256
//   mu = o[0]; log_scale = o[1]; scale = exp(clip(log_scale-4, -4.6, 5))
//
// After the first rounding step every activation is an integer-valued fp32
// (|xx| < 2^23), so layers 1/out are exact integer arithmetic -> order-independent.
// Layer 0 mimics the reference op order (fma chain over j, +b, +256*h).
//
// One thread per row. Weight indices are thread-uniform -> compiler emits
// scalar (s_load) reads; FMAs take the weight as the single SGPR operand.

__global__ __launch_bounds__(256, 4)
void armint_kernel(const float* __restrict__ x,
                   const float* __restrict__ w0, const float* __restrict__ b0,
                   const float* __restrict__ w1, const float* __restrict__ b1,
                   const float* __restrict__ wo, const float* __restrict__ bo,
                   float* __restrict__ out, int n)
{
    int r = blockIdx.x * blockDim.x + threadIdx.x;
    if (r >= n) return;

    const float4* xr = (const float4*)(x + (size_t)r * 32);
    float h[32];
    float hn[32];

    #pragma unroll
    for (int q = 0; q < 8; ++q) {
        float4 v = xr[q];
        h[4*q+0] = v.x * 256.0f;
        h[4*q+1] = v.y * 256.0f;
        h[4*q+2] = v.z * 256.0f;
        h[4*q+3] = v.w * 256.0f;
    }

    // layer 0 (residual + relu)
    #pragma unroll
    for (int i = 0; i < 32; ++i) {
        float acc = 0.0f;
        #pragma unroll
        for (int j = 0; j < 32; ++j)
            acc = fmaf(h[j], w0[i*32+j], acc);
        acc += b0[i];
        acc = fmaf(h[i], 256.0f, acc);   // h*256 is exact (pow2) -> fma == mul+add
        // relu(trunc((xx+sign(xx)*128)/256)) == max(trunc((xx+128)/256), 0)
        hn[i] = fmaxf(truncf((acc + 128.0f) * (1.0f/256.0f)), 0.0f);
    }

    // layer 1 (residual + relu) — exact integer fp32 arithmetic
    #pragma unroll
    for (int i = 0; i < 32; ++i) {
        float acc = 0.0f;
        #pragma unroll
        for (int j = 0; j < 32; ++j)
            acc = fmaf(hn[j], w1[i*32+j], acc);
        acc += b1[i];
        acc = fmaf(hn[i], 256.0f, acc);
        h[i] = fmaxf(truncf((acc + 128.0f) * (1.0f/256.0f)), 0.0f);
    }

    // output layer (no residual, no relu) — needs true sign-away rounding
    float o[2];
    #pragma unroll
    for (int i = 0; i < 2; ++i) {
        float acc = 0.0f;
        #pragma unroll
        for (int j = 0; j < 32; ++j)
            acc = fmaf(h[j], wo[i*32+j], acc);
        acc += bo[i];
        float adj = acc + copysignf(128.0f, acc);
        o[i] = truncf(adj * (1.0f/256.0f)) * (1.0f/256.0f);
    }

    float mu = o[0];
    float ls = o[1];
    float cl = fminf(fmaxf(ls - 4.0f, -4.6f), 5.0f);
    float sc = expf(cl);

    size_t nn = (size_t)n;
    out[r]          = mu;
    out[nn + r]     = sc;
    out[2*nn + r]   = ls;
}

extern "C" void kernel_launch(void* const* d_in, const int* in_sizes, int n_in,
                              void* d_out, int out_size, void* d_ws, size_t ws_size,
                              hipStream_t stream) {
    const float* x  = (const float*)d_in[0];
    const float* w0 = (const float*)d_in[1];
    const float* b0 = (const float*)d_in[2];
    const float* w1 = (const float*)d_in[3];
    const float* b1 = (const float*)d_in[4];
    const float* wo = (const float*)d_in[5];
    const float* bo = (const float*)d_in[6];
    float* out = (float*)d_out;

    int n = in_sizes[0] / 32;           // number of rows (B = 2097152)
    int block = 256;
    int grid = (n + block - 1) / block;

    armint_kernel<<<grid, block, 0, stream>>>(x, w0, b0, w1, b1, wo, bo, out, n);
}